// Round 3
// baseline (2960.114 us; speedup 1.0000x reference)
//
#include <hip/hip_runtime.h>
#include <hip/hip_bf16.h>

#define NUM_TASKS 50
#define NUM_EXPERTS 8
#define WIDTH 1024
#define FEAT 512
#define HEAD_DIM 256
#define BATCH 4096
#define XCOLS (FEAT + NUM_TASKS)   // 562

// All reference dtypes are float32 -> all I/O is fp32.

// ---------------------------------------------------------------------------
// prep: per batch row, find task id from one-hot tail of x; emb = W_emb[tid]+b_emb
// ---------------------------------------------------------------------------
__global__ void prep_kernel(const float* __restrict__ x,
                            const float* __restrict__ W_emb,
                            const float* __restrict__ b_emb,
                            float* __restrict__ emb,
                            int* __restrict__ tids) {
    int b = blockIdx.x;
    int lane = threadIdx.x;  // 64 threads, one wave
    float v = 0.f;
    if (lane < NUM_TASKS) v = x[(size_t)b * XCOLS + FEAT + lane];
    unsigned long long mask = __ballot(v > 0.5f);
    int tid = __ffsll(mask) - 1;     // one-hot: exactly one bit
    if (tid < 0) tid = 0;            // defensive clamp (no fault)
    if (tid > NUM_TASKS - 1) tid = NUM_TASKS - 1;
    if (lane == 0) tids[b] = tid;
    if (lane < NUM_EXPERTS)
        emb[(size_t)b * NUM_EXPERTS + lane] =
            W_emb[tid * NUM_EXPERTS + lane] + b_emb[lane];
}

// ---------------------------------------------------------------------------
// Generic expert-batched GEMM over a batch CHUNK (fp32 VALU, correctness-first):
//   C[r, e*1024 + n] = act( sum_k A[r*lda + e*aoff + k] * W[e,k,n] + bias[e,n] )
// grid = (CHUNK/64, WIDTH/64, 8); block = 256; tile 64x64, TK=32.
// ---------------------------------------------------------------------------
template <bool RELU>
__global__ __launch_bounds__(256) void gemm_kernel(
    const float* __restrict__ A, int lda, int aoff,
    const float* __restrict__ W, const float* __restrict__ bias,
    float* __restrict__ C, int K)
{
    const int m0 = blockIdx.x * 64;
    const int n0 = blockIdx.y * 64;
    const int e  = blockIdx.z;
    const int tid = threadIdx.x;

    __shared__ __align__(16) float As[32][68];  // [k][m], pad 64->68
    __shared__ __align__(16) float Ws[32][68];  // [k][n]

    const float* __restrict__ Ab = A + (size_t)e * aoff;
    const float* __restrict__ Wb = W + (size_t)e * K * WIDTH + n0;

    const int rm = (tid >> 4) << 2;   // row group base 0..60
    const int cn = (tid & 15) << 2;   // col group base 0..60

    float acc[4][4] = {};

    for (int kt = 0; kt < K; kt += 32) {
        // stage A tile: 64 rows x 32 k (float2 loads; rows 8B-aligned for all lda used)
        #pragma unroll
        for (int q = 0; q < 4; ++q) {
            int p = tid + 256 * q;          // 0..1023
            int ri = p >> 4;                // 0..63
            int kp = p & 15;                // 0..15 -> k pair
            float2 ra = *reinterpret_cast<const float2*>(
                Ab + (size_t)(m0 + ri) * lda + kt + 2 * kp);
            As[2 * kp][ri]     = ra.x;
            As[2 * kp + 1][ri] = ra.y;
        }
        // stage W tile: 32 k x 64 n (float4 loads, 16B aligned)
        #pragma unroll
        for (int q = 0; q < 2; ++q) {
            int g = tid + 256 * q;          // 0..511
            int ki = g >> 4;                // 0..31
            int ng = (g & 15) << 2;         // 0..60
            float4 raw = *reinterpret_cast<const float4*>(
                Wb + (size_t)(kt + ki) * WIDTH + ng);
            *reinterpret_cast<float4*>(&Ws[ki][ng]) = raw;
        }
        __syncthreads();

        #pragma unroll
        for (int ki = 0; ki < 32; ++ki) {
            float4 a = *reinterpret_cast<const float4*>(&As[ki][rm]);
            float4 w = *reinterpret_cast<const float4*>(&Ws[ki][cn]);
            acc[0][0] += a.x * w.x; acc[0][1] += a.x * w.y; acc[0][2] += a.x * w.z; acc[0][3] += a.x * w.w;
            acc[1][0] += a.y * w.x; acc[1][1] += a.y * w.y; acc[1][2] += a.y * w.z; acc[1][3] += a.y * w.w;
            acc[2][0] += a.z * w.x; acc[2][1] += a.z * w.y; acc[2][2] += a.z * w.z; acc[2][3] += a.z * w.w;
            acc[3][0] += a.w * w.x; acc[3][1] += a.w * w.y; acc[3][2] += a.w * w.z; acc[3][3] += a.w * w.w;
        }
        __syncthreads();
    }

    #pragma unroll
    for (int i = 0; i < 4; ++i) {
        size_t row = (size_t)(m0 + rm + i);
        #pragma unroll
        for (int j = 0; j < 4; ++j) {
            float v = acc[i][j] + bias[e * WIDTH + n0 + cn + j];
            if (RELU) v = fmaxf(v, 0.f);
            C[row * (NUM_EXPERTS * WIDTH) + e * WIDTH + n0 + cn + j] = v;
        }
    }
}

// ---------------------------------------------------------------------------
// Fused: classical Gram-Schmidt over 8x1024 (per batch row) + emb-weighted
// combine + ReLU + selected head GEMV. One 256-thread block per batch row.
// Thread t only touches columns {t+256q} of every vector -> no cross-thread
// syncs needed except inside block reductions.
// ---------------------------------------------------------------------------
__device__ __forceinline__ float block_reduce_sum(float x, float* scratch, int tid) {
    #pragma unroll
    for (int off = 32; off > 0; off >>= 1) x += __shfl_down(x, off, 64);
    int wave = tid >> 6;
    if ((tid & 63) == 0) scratch[wave] = x;
    __syncthreads();
    if (tid == 0) scratch[0] = scratch[0] + scratch[1] + scratch[2] + scratch[3];
    __syncthreads();
    float r = scratch[0];
    __syncthreads();   // protect scratch before next call
    return r;
}

__global__ __launch_bounds__(256) void gs_head_kernel(
    const float* __restrict__ eo,      // [CHUNK][8][1024] (bias added, linear)
    const float* __restrict__ emb,     // [CHUNK][8]
    const int* __restrict__ tids,      // [CHUNK]
    const float* __restrict__ W_head,  // [50][1024][256]
    const float* __restrict__ b_head,  // [50][256]
    float* __restrict__ out)           // [CHUNK][256]
{
    const int b = blockIdx.x;
    const int tid = threadIdx.x;

    __shared__ __align__(16) float vsh[NUM_EXPERTS * WIDTH];  // 32 KB
    __shared__ __align__(16) float feats[WIDTH];              // 4 KB
    __shared__ float scratch[4];

    // load eo[b] -> LDS (float4)
    const float4* src = reinterpret_cast<const float4*>(eo + (size_t)b * (NUM_EXPERTS * WIDTH));
    #pragma unroll
    for (int q = 0; q < 8; ++q) {
        int g = tid + 256 * q;            // 0..2047
        *reinterpret_cast<float4*>(&vsh[4 * g]) = src[g];
    }
    __syncthreads();

    // normalize vector 0
    {
        float s = 0.f;
        #pragma unroll
        for (int q = 0; q < 4; ++q) { float t = vsh[tid + 256 * q]; s += t * t; }
        s = block_reduce_sum(s, scratch, tid);
        float inv = 1.f / sqrtf(s);
        #pragma unroll
        for (int q = 0; q < 4; ++q) vsh[tid + 256 * q] *= inv;
    }

    // classical GS: coeffs vs ORIGINAL v_i (matches reference einsum order)
    for (int i = 1; i < NUM_EXPERTS; ++i) {
        float* vi = &vsh[i * WIDTH];
        float c[NUM_EXPERTS - 1];
        for (int j = 0; j < i; ++j) {
            float p = 0.f;
            #pragma unroll
            for (int q = 0; q < 4; ++q) {
                int k = tid + 256 * q;
                p += vi[k] * vsh[j * WIDTH + k];
            }
            c[j] = block_reduce_sum(p, scratch, tid);
        }
        float s = 0.f;
        #pragma unroll
        for (int q = 0; q < 4; ++q) {
            int k = tid + 256 * q;
            float w = vi[k];
            for (int j = 0; j < i; ++j) w -= c[j] * vsh[j * WIDTH + k];
            vi[k] = w;
            s += w * w;
        }
        s = block_reduce_sum(s, scratch, tid);
        float inv = 1.f / sqrtf(s);
        #pragma unroll
        for (int q = 0; q < 4; ++q) vi[tid + 256 * q] *= inv;
    }

    // feats = relu(sum_e basis_e * emb_e)
    float er[NUM_EXPERTS];
    #pragma unroll
    for (int e = 0; e < NUM_EXPERTS; ++e) er[e] = emb[(size_t)b * NUM_EXPERTS + e];
    #pragma unroll
    for (int q = 0; q < 4; ++q) {
        int k = tid + 256 * q;
        float s = 0.f;
        #pragma unroll
        for (int e = 0; e < NUM_EXPERTS; ++e) s += vsh[e * WIDTH + k] * er[e];
        feats[k] = fmaxf(s, 0.f);
    }
    __syncthreads();

    // selected head: out[b,d] = sum_k feats[k] * W_head[t,k,d] + b_head[t,d]
    int t = tids[b];
    if (t < 0) t = 0;
    if (t > NUM_TASKS - 1) t = NUM_TASKS - 1;
    const float* __restrict__ Wh = W_head + (size_t)t * WIDTH * HEAD_DIM;
    const int d = tid;  // 256 threads == HEAD_DIM
    float acc = 0.f;
    #pragma unroll 4
    for (int k = 0; k < WIDTH; k += 4) {
        float4 f = *reinterpret_cast<const float4*>(&feats[k]);
        acc += f.x * Wh[(size_t)(k + 0) * HEAD_DIM + d];
        acc += f.y * Wh[(size_t)(k + 1) * HEAD_DIM + d];
        acc += f.z * Wh[(size_t)(k + 2) * HEAD_DIM + d];
        acc += f.w * Wh[(size_t)(k + 3) * HEAD_DIM + d];
    }
    acc += b_head[t * HEAD_DIM + d];
    out[(size_t)b * HEAD_DIM + d] = acc;
}

// ---------------------------------------------------------------------------
extern "C" void kernel_launch(void* const* d_in, const int* in_sizes, int n_in,
                              void* d_out, int out_size, void* d_ws, size_t ws_size,
                              hipStream_t stream) {
    const float* x      = (const float*)d_in[0];
    const float* W_emb  = (const float*)d_in[1];
    const float* b_emb  = (const float*)d_in[2];
    const float* W0     = (const float*)d_in[3];
    const float* b0     = (const float*)d_in[4];
    const float* W1     = (const float*)d_in[5];
    const float* b1     = (const float*)d_in[6];
    const float* Wout   = (const float*)d_in[7];
    const float* bout   = (const float*)d_in[8];
    const float* W_head = (const float*)d_in[9];
    const float* b_head = (const float*)d_in[10];
    float* out = (float*)d_out;

    // ---- workspace layout: small fixed region, then two ping-pong buffers ----
    char* ws = (char*)d_ws;
    float* emb = (float*)ws;                       // 4096*8*4 = 131072 B
    int* tids  = (int*)(ws + (size_t)BATCH * NUM_EXPERTS * sizeof(float));
    const size_t FIXED = (size_t)BATCH * NUM_EXPERTS * sizeof(float)
                       + (size_t)BATCH * sizeof(int);          // 147456 B (16B mult)
    char* bufbase = ws + FIXED;

    // pick the largest chunk whose two fp32 buffers fit in the workspace
    const size_t ROWB = (size_t)NUM_EXPERTS * WIDTH * sizeof(float);  // 32768 B/row
    size_t avail = ws_size > FIXED ? ws_size - FIXED : 0;
    int CHUNK;
    if      (avail >= 2 * (size_t)4096 * ROWB) CHUNK = 4096;   // 268 MB
    else if (avail >= 2 * (size_t)1024 * ROWB) CHUNK = 1024;   //  67 MB
    else if (avail >= 2 * (size_t)256  * ROWB) CHUNK = 256;    //  17 MB
    else                                       CHUNK = 64;     //   4.2 MB

    float* bufA = (float*)bufbase;                          // h0, later eo
    float* bufB = (float*)(bufbase + (size_t)CHUNK * ROWB); // h1

    prep_kernel<<<BATCH, 64, 0, stream>>>(x, W_emb, b_emb, emb, tids);

    dim3 grid(CHUNK / 64, WIDTH / 64, NUM_EXPERTS);
    for (int r0 = 0; r0 < BATCH; r0 += CHUNK) {
        const float* xc = x + (size_t)r0 * XCOLS;
        // layer0: A = feat slice of x (lda=562), K=512, ReLU -> bufA
        gemm_kernel<true><<<grid, 256, 0, stream>>>(xc, XCOLS, 0, W0, b0, bufA, FEAT);
        // layer1: A = bufA per-expert slice, K=1024, ReLU -> bufB
        gemm_kernel<true><<<grid, 256, 0, stream>>>(bufA, NUM_EXPERTS * WIDTH, WIDTH, W1, b1, bufB, WIDTH);
        // layer out: A = bufB per-expert slice, K=1024, linear (+bout) -> bufA
        gemm_kernel<false><<<grid, 256, 0, stream>>>(bufB, NUM_EXPERTS * WIDTH, WIDTH, Wout, bout, bufA, WIDTH);
        // fused GS + combine + head for this chunk
        gs_head_kernel<<<CHUNK, 256, 0, stream>>>(bufA, emb + (size_t)r0 * NUM_EXPERTS,
                                                  tids + r0, W_head, b_head,
                                                  out + (size_t)r0 * HEAD_DIM);
    }
}

// Round 4
// 936.049 us; speedup vs baseline: 3.1624x; 3.1624x over previous
//
#include <hip/hip_runtime.h>
#include <hip/hip_bf16.h>

#define NUM_TASKS 50
#define NUM_EXPERTS 8
#define WIDTH 1024
#define FEAT 512
#define HEAD_DIM 256
#define BATCH 4096
#define XCOLS (FEAT + NUM_TASKS)   // 562

typedef unsigned short ushort_t;
typedef short bf16x8 __attribute__((ext_vector_type(8)));
typedef float f32x4 __attribute__((ext_vector_type(4)));

// fp32 -> bf16 (RNE) as raw ushort bits
__device__ __forceinline__ ushort_t f2b(float f) {
    unsigned u = __float_as_uint(f);
    unsigned r = (u + 0x7fffu + ((u >> 16) & 1u)) >> 16;
    return (ushort_t)r;
}
// bf16 bits -> fp32 (exact)
__device__ __forceinline__ float b2f_lo(unsigned u) { return __uint_as_float(u << 16); }
__device__ __forceinline__ float b2f_hi(unsigned u) { return __uint_as_float(u & 0xffff0000u); }

// async global->LDS, 16B per lane (dest must be uniform-base + lane*16; our
// mapping t*16 bytes = (wave*1024) + lane*16 satisfies this exactly)
__device__ __forceinline__ void async16(const ushort_t* g, ushort_t* l) {
    __builtin_amdgcn_global_load_lds(
        (const __attribute__((address_space(1))) unsigned int*)g,
        (__attribute__((address_space(3))) unsigned int*)l,
        16, 0, 0);
}

// ---------------------------------------------------------------------------
// prep: task id from one-hot tail; emb = W_emb[tid]+b_emb   (fp32)
// ---------------------------------------------------------------------------
__global__ void prep_kernel(const float* __restrict__ x,
                            const float* __restrict__ W_emb,
                            const float* __restrict__ b_emb,
                            float* __restrict__ emb,
                            int* __restrict__ tids) {
    int b = blockIdx.x;
    int lane = threadIdx.x;  // 64
    float v = 0.f;
    if (lane < NUM_TASKS) v = x[(size_t)b * XCOLS + FEAT + lane];
    unsigned long long mask = __ballot(v > 0.5f);
    int tid = __ffsll(mask) - 1;
    if (tid < 0) tid = 0;
    if (tid > NUM_TASKS - 1) tid = NUM_TASKS - 1;
    if (lane == 0) tids[b] = tid;
    if (lane < NUM_EXPERTS)
        emb[(size_t)b * NUM_EXPERTS + lane] =
            W_emb[tid * NUM_EXPERTS + lane] + b_emb[lane];
}

// ---------------------------------------------------------------------------
// conversions: x feat slice -> bf16 [4096][512]; W[e][K][1024] -> Wt[e][1024][K] bf16
// ---------------------------------------------------------------------------
__global__ void conv_x_kernel(const float* __restrict__ x, ushort_t* __restrict__ xb) {
    int b = blockIdx.x, t = threadIdx.x;  // 256 threads
    #pragma unroll
    for (int q = 0; q < 2; ++q) {
        int i = t + 256 * q;
        xb[(size_t)b * FEAT + i] = f2b(x[(size_t)b * XCOLS + i]);
    }
}

__global__ void conv_wt_kernel(const float* __restrict__ W, ushort_t* __restrict__ Wt, int K) {
    // grid (K/32, 1024/32, 8), block 256; 32x32 LDS-tile transpose
    int k0 = blockIdx.x * 32, n0 = blockIdx.y * 32, e = blockIdx.z;
    __shared__ float tile[32][33];
    const float* Wb = W + (size_t)e * K * WIDTH;
    ushort_t* Wtb = Wt + (size_t)e * WIDTH * K;
    int t = threadIdx.x;
    #pragma unroll
    for (int q = 0; q < 4; ++q) {
        int i = t + 256 * q; int ki = i >> 5, ni = i & 31;
        tile[ki][ni] = Wb[(size_t)(k0 + ki) * WIDTH + n0 + ni];
    }
    __syncthreads();
    #pragma unroll
    for (int q = 0; q < 4; ++q) {
        int i = t + 256 * q; int ni = i >> 5, ki = i & 31;
        Wtb[(size_t)(n0 + ni) * K + k0 + ki] = f2b(tile[ki][ni]);
    }
}

// ---------------------------------------------------------------------------
// MFMA expert-batched GEMM (m93/m97 recipe):
//   C[r, e*1024+n] = act( sum_k A[r*lda + e*aoff + k] * B[e,k,n] + bias[e,n] )
// A: bf16 [rows][lda];  Bt: bf16 [e][1024][K] (transposed weights);
// C: bf16 [rows][8192]. grid (CHUNK/128, 8, 8); block 256 (4 waves, 2x2 of 64x64).
// ---------------------------------------------------------------------------
template <bool RELU>
__global__ __launch_bounds__(256) void mfma_gemm(
    const ushort_t* __restrict__ A, int lda, int aoff,
    const ushort_t* __restrict__ Bt,
    const float* __restrict__ bias,
    ushort_t* __restrict__ C, int K)
{
    const int m0 = blockIdx.x * 128;
    const int n0 = blockIdx.y * 128;
    const int e  = blockIdx.z;
    const int t  = threadIdx.x;
    const int l  = t & 63;

    __shared__ __align__(16) ushort_t As[128 * 32];  // [m][k] 8 KB
    __shared__ __align__(16) ushort_t Bs[128 * 32];  // [n][k] 8 KB

    const ushort_t* __restrict__ Ab = A + (size_t)e * aoff + (size_t)m0 * lda;
    const ushort_t* __restrict__ Bb = Bt + ((size_t)e * WIDTH + n0) * K;

    const int srow = t >> 2;         // 0..63
    const int scol = (t & 3) * 8;    // k-element offset (16B granule)

    const int w  = t >> 6;
    const int wm = (w >> 1) * 64;    // wave row offset in tile
    const int wn = (w & 1) * 64;     // wave col offset in tile
    const int lm = l & 15;
    const int lk = (l >> 4) * 8;

    f32x4 acc[4][4];
    #pragma unroll
    for (int i = 0; i < 4; ++i)
        #pragma unroll
        for (int j = 0; j < 4; ++j) acc[i][j] = {0.f, 0.f, 0.f, 0.f};

    for (int kt = 0; kt < K; kt += 32) {
        __syncthreads();  // WAR: previous compute done before restaging
        async16(Ab + (size_t)srow * lda + kt + scol,        &As[t * 8]);
        async16(Ab + (size_t)(srow + 64) * lda + kt + scol, &As[2048 + t * 8]);
        async16(Bb + (size_t)srow * K + kt + scol,          &Bs[t * 8]);
        async16(Bb + (size_t)(srow + 64) * K + kt + scol,   &Bs[2048 + t * 8]);
        __syncthreads();  // RAW: staging complete (compiler emits vmcnt(0))

        bf16x8 af[4], bfr[4];
        #pragma unroll
        for (int mi = 0; mi < 4; ++mi)
            af[mi] = *reinterpret_cast<const bf16x8*>(&As[(wm + mi * 16 + lm) * 32 + lk]);
        #pragma unroll
        for (int ni = 0; ni < 4; ++ni)
            bfr[ni] = *reinterpret_cast<const bf16x8*>(&Bs[(wn + ni * 16 + lm) * 32 + lk]);
        #pragma unroll
        for (int mi = 0; mi < 4; ++mi)
            #pragma unroll
            for (int ni = 0; ni < 4; ++ni)
                acc[mi][ni] = __builtin_amdgcn_mfma_f32_16x16x32_bf16(
                    af[mi], bfr[ni], acc[mi][ni], 0, 0, 0);
    }

    // epilogue: C/D layout col=lane&15, row=(lane>>4)*4+reg  [m89-verified]
    const int rbase = (l >> 4) * 4;
    #pragma unroll
    for (int mi = 0; mi < 4; ++mi) {
        #pragma unroll
        for (int ni = 0; ni < 4; ++ni) {
            int col = n0 + wn + ni * 16 + lm;           // 0..1023 expert-local
            float bv = bias[e * WIDTH + col];
            #pragma unroll
            for (int r = 0; r < 4; ++r) {
                int row = m0 + wm + mi * 16 + rbase + r;
                float v = acc[mi][ni][r] + bv;
                if (RELU) v = fmaxf(v, 0.f);
                C[(size_t)row * (NUM_EXPERTS * WIDTH) + e * WIDTH + col] = f2b(v);
            }
        }
    }
}

// ---------------------------------------------------------------------------
// Fused GS + combine + selected head GEMV (fp32 math; eo now bf16)
// ---------------------------------------------------------------------------
__device__ __forceinline__ float block_reduce_sum(float x, float* scratch, int tid) {
    #pragma unroll
    for (int off = 32; off > 0; off >>= 1) x += __shfl_down(x, off, 64);
    int wave = tid >> 6;
    if ((tid & 63) == 0) scratch[wave] = x;
    __syncthreads();
    if (tid == 0) scratch[0] = scratch[0] + scratch[1] + scratch[2] + scratch[3];
    __syncthreads();
    float r = scratch[0];
    __syncthreads();
    return r;
}

__global__ __launch_bounds__(256) void gs_head_kernel(
    const ushort_t* __restrict__ eo,   // [CHUNK][8][1024] bf16
    const float* __restrict__ emb,     // [CHUNK][8]
    const int* __restrict__ tids,      // [CHUNK]
    const float* __restrict__ W_head,  // [50][1024][256] fp32
    const float* __restrict__ b_head,  // [50][256] fp32
    float* __restrict__ out)           // [CHUNK][256] fp32
{
    const int b = blockIdx.x;
    const int tid = threadIdx.x;

    __shared__ __align__(16) float vsh[NUM_EXPERTS * WIDTH];  // 32 KB
    __shared__ __align__(16) float feats[WIDTH];
    __shared__ float scratch[4];

    const uint2* src = reinterpret_cast<const uint2*>(eo + (size_t)b * (NUM_EXPERTS * WIDTH));
    #pragma unroll
    for (int q = 0; q < 8; ++q) {
        int g = tid + 256 * q;            // 0..2047, 4 bf16 each
        uint2 raw = src[g];
        float4 f;
        f.x = b2f_lo(raw.x); f.y = b2f_hi(raw.x);
        f.z = b2f_lo(raw.y); f.w = b2f_hi(raw.y);
        *reinterpret_cast<float4*>(&vsh[4 * g]) = f;
    }
    __syncthreads();

    {   // normalize v0
        float s = 0.f;
        #pragma unroll
        for (int q = 0; q < 4; ++q) { float v = vsh[tid + 256 * q]; s += v * v; }
        s = block_reduce_sum(s, scratch, tid);
        float inv = 1.f / sqrtf(s);
        #pragma unroll
        for (int q = 0; q < 4; ++q) vsh[tid + 256 * q] *= inv;
    }

    for (int i = 1; i < NUM_EXPERTS; ++i) {
        float* vi = &vsh[i * WIDTH];
        float c[NUM_EXPERTS - 1];
        for (int j = 0; j < i; ++j) {
            float p = 0.f;
            #pragma unroll
            for (int q = 0; q < 4; ++q) {
                int k = tid + 256 * q;
                p += vi[k] * vsh[j * WIDTH + k];
            }
            c[j] = block_reduce_sum(p, scratch, tid);
        }
        float s = 0.f;
        #pragma unroll
        for (int q = 0; q < 4; ++q) {
            int k = tid + 256 * q;
            float wv = vi[k];
            for (int j = 0; j < i; ++j) wv -= c[j] * vsh[j * WIDTH + k];
            vi[k] = wv;
            s += wv * wv;
        }
        s = block_reduce_sum(s, scratch, tid);
        float inv = 1.f / sqrtf(s);
        #pragma unroll
        for (int q = 0; q < 4; ++q) vi[tid + 256 * q] *= inv;
    }

    float er[NUM_EXPERTS];
    #pragma unroll
    for (int e = 0; e < NUM_EXPERTS; ++e) er[e] = emb[(size_t)b * NUM_EXPERTS + e];
    #pragma unroll
    for (int q = 0; q < 4; ++q) {
        int k = tid + 256 * q;
        float s = 0.f;
        #pragma unroll
        for (int e = 0; e < NUM_EXPERTS; ++e) s += vsh[e * WIDTH + k] * er[e];
        feats[k] = fmaxf(s, 0.f);
    }
    __syncthreads();

    int tk = tids[b];
    if (tk < 0) tk = 0;
    if (tk > NUM_TASKS - 1) tk = NUM_TASKS - 1;
    const float* __restrict__ Wh = W_head + (size_t)tk * WIDTH * HEAD_DIM;
    const int d = tid;
    float acc = 0.f;
    #pragma unroll 4
    for (int k = 0; k < WIDTH; k += 4) {
        float4 f = *reinterpret_cast<const float4*>(&feats[k]);
        acc += f.x * Wh[(size_t)(k + 0) * HEAD_DIM + d];
        acc += f.y * Wh[(size_t)(k + 1) * HEAD_DIM + d];
        acc += f.z * Wh[(size_t)(k + 2) * HEAD_DIM + d];
        acc += f.w * Wh[(size_t)(k + 3) * HEAD_DIM + d];
    }
    acc += b_head[tk * HEAD_DIM + d];
    out[(size_t)b * HEAD_DIM + d] = acc;
}

// ---------------------------------------------------------------------------
extern "C" void kernel_launch(void* const* d_in, const int* in_sizes, int n_in,
                              void* d_out, int out_size, void* d_ws, size_t ws_size,
                              hipStream_t stream) {
    const float* x      = (const float*)d_in[0];
    const float* W_emb  = (const float*)d_in[1];
    const float* b_emb  = (const float*)d_in[2];
    const float* W0     = (const float*)d_in[3];
    const float* b0     = (const float*)d_in[4];
    const float* W1     = (const float*)d_in[5];
    const float* b1     = (const float*)d_in[6];
    const float* Wout   = (const float*)d_in[7];
    const float* bout   = (const float*)d_in[8];
    const float* W_head = (const float*)d_in[9];
    const float* b_head = (const float*)d_in[10];
    float* out = (float*)d_out;

    // ---- workspace layout ----
    char* ws = (char*)d_ws;
    float* emb = (float*)ws;
    int* tids  = (int*)(ws + (size_t)BATCH * NUM_EXPERTS * sizeof(float));
    size_t off = (size_t)BATCH * NUM_EXPERTS * sizeof(float) + (size_t)BATCH * sizeof(int); // 147456
    ushort_t* xb    = (ushort_t*)(ws + off); off += (size_t)BATCH * FEAT * 2;               // 4.19 MB
    ushort_t* W0t   = (ushort_t*)(ws + off); off += (size_t)NUM_EXPERTS * WIDTH * FEAT * 2; // 8.39 MB
    ushort_t* W1t   = (ushort_t*)(ws + off); off += (size_t)NUM_EXPERTS * WIDTH * WIDTH * 2;// 16.8 MB
    ushort_t* Woutt = (ushort_t*)(ws + off); off += (size_t)NUM_EXPERTS * WIDTH * WIDTH * 2;// 16.8 MB
    char* bufbase = ws + off;                                                                // 46.3 MB fixed

    const size_t ROWB = (size_t)NUM_EXPERTS * WIDTH * 2;  // 16384 B/row (bf16)
    size_t avail = ws_size > off ? ws_size - off : 0;
    int CHUNK;
    if      (avail >= 2 * (size_t)4096 * ROWB) CHUNK = 4096;  // 180.5 MB total
    else if (avail >= 2 * (size_t)2048 * ROWB) CHUNK = 2048;  // 113.4 MB
    else if (avail >= 2 * (size_t)1024 * ROWB) CHUNK = 1024;  //  79.8 MB
    else                                       CHUNK = 512;   //  63.1 MB (fits known ws >= 67.3 MB)

    ushort_t* bufA = (ushort_t*)bufbase;                          // h0, later eo
    ushort_t* bufB = (ushort_t*)(bufbase + (size_t)CHUNK * ROWB); // h1

    prep_kernel<<<BATCH, 64, 0, stream>>>(x, W_emb, b_emb, emb, tids);
    conv_x_kernel<<<BATCH, 256, 0, stream>>>(x, xb);
    conv_wt_kernel<<<dim3(FEAT / 32, WIDTH / 32, NUM_EXPERTS), 256, 0, stream>>>(W0, W0t, FEAT);
    conv_wt_kernel<<<dim3(WIDTH / 32, WIDTH / 32, NUM_EXPERTS), 256, 0, stream>>>(W1, W1t, WIDTH);
    conv_wt_kernel<<<dim3(WIDTH / 32, WIDTH / 32, NUM_EXPERTS), 256, 0, stream>>>(Wout, Woutt, WIDTH);

    dim3 grid(CHUNK / 128, WIDTH / 128, NUM_EXPERTS);
    for (int r0 = 0; r0 < BATCH; r0 += CHUNK) {
        const ushort_t* xc = xb + (size_t)r0 * FEAT;
        mfma_gemm<true ><<<grid, 256, 0, stream>>>(xc, FEAT, 0, W0t, b0, bufA, FEAT);
        mfma_gemm<true ><<<grid, 256, 0, stream>>>(bufA, NUM_EXPERTS * WIDTH, WIDTH, W1t, b1, bufB, WIDTH);
        mfma_gemm<false><<<grid, 256, 0, stream>>>(bufB, NUM_EXPERTS * WIDTH, WIDTH, Woutt, bout, bufA, WIDTH);
        gs_head_kernel<<<CHUNK, 256, 0, stream>>>(bufA, emb + (size_t)r0 * NUM_EXPERTS,
                                                  tids + r0, W_head, b_head,
                                                  out + (size_t)r0 * HEAD_DIM);
    }
}

// Round 5
// 586.969 us; speedup vs baseline: 5.0431x; 1.5947x over previous
//
#include <hip/hip_runtime.h>
#include <hip/hip_bf16.h>

#define NUM_TASKS 50
#define NUM_EXPERTS 8
#define WIDTH 1024
#define FEAT 512
#define HEAD_DIM 256
#define BATCH 4096
#define XCOLS (FEAT + NUM_TASKS)   // 562
#define MAXGRP 576                 // >= 512 + 50 hard bound on ceil-groups of 8

typedef unsigned short ushort_t;
typedef short bf16x8 __attribute__((ext_vector_type(8)));
typedef float f32x4 __attribute__((ext_vector_type(4)));

// fp32 -> bf16 (RNE) raw bits
__device__ __forceinline__ ushort_t f2b(float f) {
    unsigned u = __float_as_uint(f);
    unsigned r = (u + 0x7fffu + ((u >> 16) & 1u)) >> 16;
    return (ushort_t)r;
}
__device__ __forceinline__ float b2f_lo(unsigned u) { return __uint_as_float(u << 16); }
__device__ __forceinline__ float b2f_hi(unsigned u) { return __uint_as_float(u & 0xffff0000u); }

__device__ __forceinline__ void async16(const ushort_t* g, ushort_t* l) {
    __builtin_amdgcn_global_load_lds(
        (const __attribute__((address_space(1))) unsigned int*)g,
        (__attribute__((address_space(3))) unsigned int*)l,
        16, 0, 0);
}

// ---------------------------------------------------------------------------
// prep: task id + emb
// ---------------------------------------------------------------------------
__global__ void prep_kernel(const float* __restrict__ x,
                            const float* __restrict__ W_emb,
                            const float* __restrict__ b_emb,
                            float* __restrict__ emb,
                            int* __restrict__ tids) {
    int b = blockIdx.x;
    int lane = threadIdx.x;  // 64
    float v = 0.f;
    if (lane < NUM_TASKS) v = x[(size_t)b * XCOLS + FEAT + lane];
    unsigned long long mask = __ballot(v > 0.5f);
    int tid = __ffsll(mask) - 1;
    if (tid < 0) tid = 0;
    if (tid > NUM_TASKS - 1) tid = NUM_TASKS - 1;
    if (lane == 0) tids[b] = tid;
    if (lane < NUM_EXPERTS)
        emb[(size_t)b * NUM_EXPERTS + lane] =
            W_emb[tid * NUM_EXPERTS + lane] + b_emb[lane];
}

// ---------------------------------------------------------------------------
// counting sort by task + group table (groups of <=8 same-task sorted rows)
// single block, 256 threads
// ---------------------------------------------------------------------------
__global__ void sort_kernel(const int* __restrict__ tids,
                            int* __restrict__ pos,      // [BATCH] b -> sorted slot
                            int* __restrict__ row_map,  // [BATCH] sorted slot -> b
                            int* __restrict__ grp,      // [MAXGRP][3] task,start,cnt
                            int* __restrict__ ngroups) {
    __shared__ int cnt[NUM_TASKS];
    __shared__ int start[NUM_TASKS];
    __shared__ int rank[NUM_TASKS];
    int t = threadIdx.x;
    if (t < NUM_TASKS) { cnt[t] = 0; rank[t] = 0; }
    __syncthreads();
    for (int b = t; b < BATCH; b += 256) atomicAdd(&cnt[tids[b]], 1);
    __syncthreads();
    if (t == 0) {
        int acc = 0, ng = 0;
        for (int k = 0; k < NUM_TASKS; ++k) {
            start[k] = acc;
            int c = cnt[k];
            for (int o = 0; o < c; o += 8) {
                int rem = c - o;
                grp[3 * ng + 0] = k;
                grp[3 * ng + 1] = acc + o;
                grp[3 * ng + 2] = rem < 8 ? rem : 8;
                ++ng;
            }
            acc += c;
        }
        *ngroups = ng;
    }
    __syncthreads();
    for (int b = t; b < BATCH; b += 256) {
        int tk = tids[b];
        int p = start[tk] + atomicAdd(&rank[tk], 1);
        pos[b] = p;
        row_map[p] = b;
    }
}

// ---------------------------------------------------------------------------
// conversions
// ---------------------------------------------------------------------------
__global__ void conv_x_kernel(const float* __restrict__ x, ushort_t* __restrict__ xb) {
    int b = blockIdx.x, t = threadIdx.x;
    #pragma unroll
    for (int q = 0; q < 2; ++q) {
        int i = t + 256 * q;
        xb[(size_t)b * FEAT + i] = f2b(x[(size_t)b * XCOLS + i]);
    }
}

__global__ void conv_wt_kernel(const float* __restrict__ W, ushort_t* __restrict__ Wt, int K) {
    int k0 = blockIdx.x * 32, n0 = blockIdx.y * 32, e = blockIdx.z;
    __shared__ float tile[32][33];
    const float* Wb = W + (size_t)e * K * WIDTH;
    ushort_t* Wtb = Wt + (size_t)e * WIDTH * K;
    int t = threadIdx.x;
    #pragma unroll
    for (int q = 0; q < 4; ++q) {
        int i = t + 256 * q; int ki = i >> 5, ni = i & 31;
        tile[ki][ni] = Wb[(size_t)(k0 + ki) * WIDTH + n0 + ni];
    }
    __syncthreads();
    #pragma unroll
    for (int q = 0; q < 4; ++q) {
        int i = t + 256 * q; int ni = i >> 5, ki = i & 31;
        Wtb[(size_t)(n0 + ni) * K + k0 + ki] = f2b(tile[ki][ni]);
    }
}

// ---------------------------------------------------------------------------
// MFMA expert-batched GEMM (unchanged from round 4 - passing)
// ---------------------------------------------------------------------------
template <bool RELU>
__global__ __launch_bounds__(256) void mfma_gemm(
    const ushort_t* __restrict__ A, int lda, int aoff,
    const ushort_t* __restrict__ Bt,
    const float* __restrict__ bias,
    ushort_t* __restrict__ C, int K)
{
    const int m0 = blockIdx.x * 128;
    const int n0 = blockIdx.y * 128;
    const int e  = blockIdx.z;
    const int t  = threadIdx.x;
    const int l  = t & 63;

    __shared__ __align__(16) ushort_t As[128 * 32];
    __shared__ __align__(16) ushort_t Bs[128 * 32];

    const ushort_t* __restrict__ Ab = A + (size_t)e * aoff + (size_t)m0 * lda;
    const ushort_t* __restrict__ Bb = Bt + ((size_t)e * WIDTH + n0) * K;

    const int srow = t >> 2;
    const int scol = (t & 3) * 8;

    const int w  = t >> 6;
    const int wm = (w >> 1) * 64;
    const int wn = (w & 1) * 64;
    const int lm = l & 15;
    const int lk = (l >> 4) * 8;

    f32x4 acc[4][4];
    #pragma unroll
    for (int i = 0; i < 4; ++i)
        #pragma unroll
        for (int j = 0; j < 4; ++j) acc[i][j] = {0.f, 0.f, 0.f, 0.f};

    for (int kt = 0; kt < K; kt += 32) {
        __syncthreads();
        async16(Ab + (size_t)srow * lda + kt + scol,        &As[t * 8]);
        async16(Ab + (size_t)(srow + 64) * lda + kt + scol, &As[2048 + t * 8]);
        async16(Bb + (size_t)srow * K + kt + scol,          &Bs[t * 8]);
        async16(Bb + (size_t)(srow + 64) * K + kt + scol,   &Bs[2048 + t * 8]);
        __syncthreads();

        bf16x8 af[4], bfr[4];
        #pragma unroll
        for (int mi = 0; mi < 4; ++mi)
            af[mi] = *reinterpret_cast<const bf16x8*>(&As[(wm + mi * 16 + lm) * 32 + lk]);
        #pragma unroll
        for (int ni = 0; ni < 4; ++ni)
            bfr[ni] = *reinterpret_cast<const bf16x8*>(&Bs[(wn + ni * 16 + lm) * 32 + lk]);
        #pragma unroll
        for (int mi = 0; mi < 4; ++mi)
            #pragma unroll
            for (int ni = 0; ni < 4; ++ni)
                acc[mi][ni] = __builtin_amdgcn_mfma_f32_16x16x32_bf16(
                    af[mi], bfr[ni], acc[mi][ni], 0, 0, 0);
    }

    const int rbase = (l >> 4) * 4;
    #pragma unroll
    for (int mi = 0; mi < 4; ++mi) {
        #pragma unroll
        for (int ni = 0; ni < 4; ++ni) {
            int col = n0 + wn + ni * 16 + lm;
            float bv = bias[e * WIDTH + col];
            #pragma unroll
            for (int r = 0; r < 4; ++r) {
                int row = m0 + wm + mi * 16 + rbase + r;
                float v = acc[mi][ni][r] + bv;
                if (RELU) v = fmaxf(v, 0.f);
                C[(size_t)row * (NUM_EXPERTS * WIDTH) + e * WIDTH + col] = f2b(v);
            }
        }
    }
}

// ---------------------------------------------------------------------------
// Wave-per-row Gram-Schmidt, all in registers. 4 waves/block, grid CHUNK/4.
// Lane l owns elements k = l*16 + j (j=0..15) of every vector. 36 reductions
// are 6-step __shfl_xor butterflies - no barriers, no LDS.
// Writes feats (fp32) to the task-SORTED slot pos[b] of featsS.
// ---------------------------------------------------------------------------
__device__ __forceinline__ float wave_sum(float x) {
    #pragma unroll
    for (int off = 1; off < 64; off <<= 1) x += __shfl_xor(x, off, 64);
    return x;
}
__device__ __forceinline__ void u2f8(uint4 a, float* f) {
    f[0] = b2f_lo(a.x); f[1] = b2f_hi(a.x);
    f[2] = b2f_lo(a.y); f[3] = b2f_hi(a.y);
    f[4] = b2f_lo(a.z); f[5] = b2f_hi(a.z);
    f[6] = b2f_lo(a.w); f[7] = b2f_hi(a.w);
}

__global__ __launch_bounds__(256, 1) void gs_wave_kernel(
    const ushort_t* __restrict__ eo,   // [CHUNK][8][1024] bf16 (chunk-local)
    const float* __restrict__ emb,     // [CHUNK][8] (chunk offset applied)
    const int* __restrict__ pos,       // [CHUNK] global sorted slot
    float* __restrict__ featsS)        // [BATCH][1024] fp32 (global base)
{
    const int w = threadIdx.x >> 6;
    const int l = threadIdx.x & 63;
    const int r = blockIdx.x * 4 + w;

    float v[NUM_EXPERTS][16];
    const ushort_t* row = eo + (size_t)r * (NUM_EXPERTS * WIDTH);
    #pragma unroll
    for (int e = 0; e < NUM_EXPERTS; ++e) {
        const uint4* p = reinterpret_cast<const uint4*>(row + e * WIDTH + l * 16);
        u2f8(p[0], &v[e][0]);
        u2f8(p[1], &v[e][8]);
    }

    // normalize v0
    {
        float s = 0.f;
        #pragma unroll
        for (int j = 0; j < 16; ++j) s += v[0][j] * v[0][j];
        s = wave_sum(s);
        float inv = 1.f / sqrtf(s);
        #pragma unroll
        for (int j = 0; j < 16; ++j) v[0][j] *= inv;
    }

    // classical GS, coeffs vs ORIGINAL v_i (reference order)
    #pragma unroll
    for (int i = 1; i < NUM_EXPERTS; ++i) {
        float c[NUM_EXPERTS];
        #pragma unroll
        for (int jj = 0; jj < i; ++jj) {
            float p = 0.f;
            #pragma unroll
            for (int j = 0; j < 16; ++j) p += v[i][j] * v[jj][j];
            c[jj] = wave_sum(p);
        }
        float s = 0.f;
        #pragma unroll
        for (int j = 0; j < 16; ++j) {
            float wv = v[i][j];
            #pragma unroll
            for (int jj = 0; jj < i; ++jj) wv -= c[jj] * v[jj][j];
            v[i][j] = wv;
            s += wv * wv;
        }
        s = wave_sum(s);
        float inv = 1.f / sqrtf(s);
        #pragma unroll
        for (int j = 0; j < 16; ++j) v[i][j] *= inv;
    }

    // feats = relu(sum_e v[e] * emb[e]); store to sorted slot
    float er[NUM_EXPERTS];
    #pragma unroll
    for (int e = 0; e < NUM_EXPERTS; ++e) er[e] = emb[(size_t)r * NUM_EXPERTS + e];
    float f[16];
    #pragma unroll
    for (int j = 0; j < 16; ++j) {
        float s = 0.f;
        #pragma unroll
        for (int e = 0; e < NUM_EXPERTS; ++e) s += v[e][j] * er[e];
        f[j] = fmaxf(s, 0.f);
    }
    int p = pos[r];
    float4* dst = reinterpret_cast<float4*>(featsS + (size_t)p * WIDTH + l * 16);
    #pragma unroll
    for (int q = 0; q < 4; ++q) dst[q] = *reinterpret_cast<float4*>(&f[4 * q]);
}

// ---------------------------------------------------------------------------
// Task-grouped head: one block per group of <=8 same-task sorted rows.
// W_head[t] streamed ONCE per 8 rows; consecutive blocks share t (L2-hot).
// fp32 throughout.
// ---------------------------------------------------------------------------
__global__ __launch_bounds__(256) void head_kernel(
    const float* __restrict__ featsS,   // [BATCH][1024] sorted
    const int* __restrict__ row_map,    // sorted slot -> b
    const int* __restrict__ grp,
    const int* __restrict__ ngroups,
    const float* __restrict__ W_head,   // [50][1024][256]
    const float* __restrict__ b_head,   // [50][256]
    float* __restrict__ out)            // [BATCH][256]
{
    const int g = blockIdx.x;
    if (g >= *ngroups) return;
    const int t   = grp[3 * g + 0];
    const int s0  = grp[3 * g + 1];
    const int cnt = grp[3 * g + 2];
    const int d = threadIdx.x;

    __shared__ __align__(16) float fs[8][WIDTH];  // 32 KB
    for (int r = 0; r < cnt; ++r) {
        const float4* srcp = reinterpret_cast<const float4*>(featsS + (size_t)(s0 + r) * WIDTH);
        reinterpret_cast<float4*>(&fs[r][0])[d] = srcp[d];
    }
    __syncthreads();

    const float* __restrict__ Wh = W_head + (size_t)t * WIDTH * HEAD_DIM;
    float acc[8] = {};
    #pragma unroll 4
    for (int k = 0; k < WIDTH; ++k) {
        float wv = Wh[(size_t)k * HEAD_DIM + d];
        #pragma unroll
        for (int r = 0; r < 8; ++r) acc[r] += fs[r][k] * wv;
    }
    float bb = b_head[t * HEAD_DIM + d];
    for (int r = 0; r < cnt; ++r)
        out[(size_t)row_map[s0 + r] * HEAD_DIM + d] = acc[r] + bb;
}

// ---------------------------------------------------------------------------
extern "C" void kernel_launch(void* const* d_in, const int* in_sizes, int n_in,
                              void* d_out, int out_size, void* d_ws, size_t ws_size,
                              hipStream_t stream) {
    const float* x      = (const float*)d_in[0];
    const float* W_emb  = (const float*)d_in[1];
    const float* b_emb  = (const float*)d_in[2];
    const float* W0     = (const float*)d_in[3];
    const float* b0     = (const float*)d_in[4];
    const float* W1     = (const float*)d_in[5];
    const float* b1     = (const float*)d_in[6];
    const float* Wout   = (const float*)d_in[7];
    const float* bout   = (const float*)d_in[8];
    const float* W_head = (const float*)d_in[9];
    const float* b_head = (const float*)d_in[10];
    float* out = (float*)d_out;

    // ---- workspace layout (all offsets 256B-aligned) ----
    char* ws = (char*)d_ws;
    size_t off = 0;
    auto take = [&](size_t bytes) { char* p = ws + off; off += (bytes + 255) & ~(size_t)255; return p; };
    float*    emb     = (float*)   take((size_t)BATCH * NUM_EXPERTS * sizeof(float));
    int*      tids    = (int*)     take((size_t)BATCH * sizeof(int));
    int*      pos     = (int*)     take((size_t)BATCH * sizeof(int));
    int*      row_map = (int*)     take((size_t)BATCH * sizeof(int));
    int*      grp     = (int*)     take((size_t)MAXGRP * 3 * sizeof(int));
    int*      ngrp    = (int*)     take(256);
    ushort_t* xb      = (ushort_t*)take((size_t)BATCH * FEAT * 2);
    ushort_t* W0t     = (ushort_t*)take((size_t)NUM_EXPERTS * WIDTH * FEAT * 2);
    ushort_t* W1t     = (ushort_t*)take((size_t)NUM_EXPERTS * WIDTH * WIDTH * 2);
    ushort_t* Woutt   = (ushort_t*)take((size_t)NUM_EXPERTS * WIDTH * WIDTH * 2);
    float*    featsS  = (float*)   take((size_t)BATCH * WIDTH * sizeof(float));
    char* bufbase = ws + off;

    const size_t ROWB = (size_t)NUM_EXPERTS * WIDTH * 2;  // 16 KB/row
    size_t avail = ws_size > off ? ws_size - off : 0;
    int CHUNK;
    if      (avail >= 2 * (size_t)4096 * ROWB) CHUNK = 4096;  // total ~197 MB
    else if (avail >= 2 * (size_t)2048 * ROWB) CHUNK = 2048;  // ~130 MB
    else if (avail >= 2 * (size_t)1024 * ROWB) CHUNK = 1024;  // ~97 MB
    else                                       CHUNK = 512;

    ushort_t* bufA = (ushort_t*)bufbase;
    ushort_t* bufB = (ushort_t*)(bufbase + (size_t)CHUNK * ROWB);

    prep_kernel<<<BATCH, 64, 0, stream>>>(x, W_emb, b_emb, emb, tids);
    sort_kernel<<<1, 256, 0, stream>>>(tids, pos, row_map, grp, ngrp);
    conv_x_kernel<<<BATCH, 256, 0, stream>>>(x, xb);
    conv_wt_kernel<<<dim3(FEAT / 32, WIDTH / 32, NUM_EXPERTS), 256, 0, stream>>>(W0, W0t, FEAT);
    conv_wt_kernel<<<dim3(WIDTH / 32, WIDTH / 32, NUM_EXPERTS), 256, 0, stream>>>(W1, W1t, WIDTH);
    conv_wt_kernel<<<dim3(WIDTH / 32, WIDTH / 32, NUM_EXPERTS), 256, 0, stream>>>(Wout, Woutt, WIDTH);

    dim3 grid(CHUNK / 128, WIDTH / 128, NUM_EXPERTS);
    for (int r0 = 0; r0 < BATCH; r0 += CHUNK) {
        const ushort_t* xc = xb + (size_t)r0 * FEAT;
        mfma_gemm<true ><<<grid, 256, 0, stream>>>(xc, FEAT, 0, W0t, b0, bufA, FEAT);
        mfma_gemm<true ><<<grid, 256, 0, stream>>>(bufA, NUM_EXPERTS * WIDTH, WIDTH, W1t, b1, bufB, WIDTH);
        mfma_gemm<false><<<grid, 256, 0, stream>>>(bufB, NUM_EXPERTS * WIDTH, WIDTH, Woutt, bout, bufA, WIDTH);
        gs_wave_kernel<<<CHUNK / 4, 256, 0, stream>>>(bufA, emb + (size_t)r0 * NUM_EXPERTS,
                                                      pos + r0, featsS);
    }
    head_kernel<<<MAXGRP, 256, 0, stream>>>(featsS, row_map, grp, ngrp, W_head, b_head, out);
}